// Round 11
// baseline (79.851 us; speedup 1.0000x reference)
//
#include <hip/hip_runtime.h>
#include <hip/hip_bf16.h>

// ---- problem constants ----
#define TLEN   524288
#define NBATCH 16
#define KSZ    1024
#define NBINS  513
#define NCH    1026
#define NFRM   2045
#define HOP    256
#define MROWS  1024        // g<512: cos c=g | g 512..1022: sin c=g-511 | g=1023: 0
#define KS2    512         // folded K
#define NFPAD  2048        // u/v frame rows per batch
// ---- GEMM tiling (256x256, BK=64, 8 waves) ----
#define BM 256
#define BN 256
#define BK 64
#define NT 8               // K-tiles (512/64)
#define LDS_BYTES 131072

typedef __bf16 bf16x8 __attribute__((ext_vector_type(8)));
typedef float  f32x4  __attribute__((ext_vector_type(4)));
typedef unsigned short us8 __attribute__((ext_vector_type(8)));

__device__ __forceinline__ unsigned short f2b(float f) {
    return __builtin_bit_cast(unsigned short, __float2bfloat16(f));
}

// ------------------------------------------------------------------
// Kernel 1: folded basis, 1024 x 512 bf16 (r7-verified).
// ------------------------------------------------------------------
__global__ void build_basis_k(const float* __restrict__ window,
                              __hip_bfloat16* __restrict__ basis) {
    int idx = blockIdx.x * 256 + threadIdx.x;
    if (idx >= MROWS * KS2) return;
    int g = idx >> 9;
    int k = idx & (KS2 - 1);
    float val = 0.0f;
    if (g < 512) {
        if (k == 0) val = (g & 1) ? -1.0f : 1.0f;
        else {
            int m = (g * k) & (KSZ - 1);
            val = window[k] * cosf((float)m * (6.283185307179586f / (float)KSZ));
        }
    } else if (g < 1023) {
        if (k != 0) {
            int c = g - 511;
            int m = (c * k) & (KSZ - 1);
            val = -window[k] * sinf((float)m * (6.283185307179586f / (float)KSZ));
        }
    }
    basis[idx] = __float2bfloat16(val);
}

// ------------------------------------------------------------------
// Kernel 2: prefold + in-wave Nyquist (r9/r10-verified).
// ------------------------------------------------------------------
__global__ void prefold_k(const float* __restrict__ x,
                          const float* __restrict__ window,
                          __hip_bfloat16* __restrict__ u,
                          __hip_bfloat16* __restrict__ v,
                          float* __restrict__ out) {
    int idx = blockIdx.x * 256 + threadIdx.x;   // NBATCH*2048*64 exact
    if (idx >= NBATCH * NFPAD * 64) return;
    int b = idx >> 17;
    int rem = idx & ((1 << 17) - 1);
    int f = rem >> 6;
    int c = rem & 63;                            // k-chunk of 8 == lane
    size_t orow = ((size_t)b * NFPAD + f) * KS2 + c * 8;
    us8 uo = {0, 0, 0, 0, 0, 0, 0, 0};
    us8 vo = {0, 0, 0, 0, 0, 0, 0, 0};
    float nacc = 0.0f;
    if (f < NFRM) {
        const float* xp = x + (size_t)b * TLEN + (size_t)f * HOP;
        float4 fw0 = *(const float4*)(xp + c * 8);
        float4 fw1 = *(const float4*)(xp + c * 8 + 4);
        float4 m0  = *(const float4*)(xp + 1016 - c * 8);
        float4 m1  = *(const float4*)(xp + 1020 - c * 8);
        float fwv[8] = {fw0.x, fw0.y, fw0.z, fw0.w,
                        fw1.x, fw1.y, fw1.z, fw1.w};
        float mv[9];
        mv[0] = m0.x; mv[1] = m0.y; mv[2] = m0.z; mv[3] = m0.w;
        mv[4] = m1.x; mv[5] = m1.y; mv[6] = m1.z; mv[7] = m1.w;
        mv[8] = (c > 0) ? xp[1024 - c * 8] : 0.0f;
        #pragma unroll
        for (int e = 0; e < 8; ++e) {
            float xf = fwv[e];
            float xm = mv[8 - e];
            float uval = xf + xm;
            uo[e] = f2b(uval);
            vo[e] = f2b(xf - xm);
            float wk = window[c * 8 + e];
            nacc += ((e & 1) ? -wk : wk) * uval;
        }
        if (c == 0) {
            float x512 = xp[512];
            uo[0] = f2b(x512);
            vo[0] = 0;
            nacc += x512;
        }
    }
    *(us8*)((unsigned short*)u + orow) = uo;
    *(us8*)((unsigned short*)v + orow) = vo;
    #pragma unroll
    for (int o = 32; o > 0; o >>= 1) nacc += __shfl_xor(nacc, o);
    if (f < NFRM) {
        if (c == 0) out[((size_t)b * NCH + 512) * NFRM + f] = nacc;
        if (c == 1) out[((size_t)b * NCH + 513) * NFRM + f] = 0.0f;
    }
}

// ------------------------------------------------------------------
// Kernel 3: folded GEMM — 4-barrier tile body (was 8).
// Regions per tile v (buffer PAR):
//  S1: stage A1(v+1,NPAR); LOAD_BFR(PAR) [properly fenced: all waves'
//      vmcnt+BAR for tile v's B happened last tile]; ldA(0)
//  BAR1
//  M1: stage B0(v+2,PAR) [BFR readers done at BAR1]; mmac0; ldA(1); mmac1
//  BAR2  [all A-h0 reads done]
//  S2: stage B1(v+2,PAR), A0(v+2,PAR -> overwrites A-h0, safe]; ldA(2)
//  BAR3
//  M2: mmac2; ldA(3) [A-h1, no concurrent writer]; mmac3; vmcnt(6|0)
//  BAR4
// Stage issue order per tile unchanged (A1,B0,B1,A0) -> r5 vmcnt
// ledger carries over verbatim. Registers unchanged (at 256/wave cap).
// ------------------------------------------------------------------
extern __shared__ char smem[];

#define BAR() __builtin_amdgcn_s_barrier()

#define LOAD_BFR(PAR)                                                       \
  { _Pragma("unroll") for (int ni = 0; ni < 4; ++ni) {                      \
      bfr[ni][0] = *(const bf16x8*)(Bs + (PAR) + ni * 2048 + bk0);          \
      bfr[ni][1] = *(const bf16x8*)(Bs + (PAR) + ni * 2048 + bk1); } }

#define LOAD_AFRQ(q, PAR)                                                   \
  { _Pragma("unroll") for (int mi = 0; mi < 2; ++mi) {                      \
      afr[mi][0] = *(const bf16x8*)(As + (PAR) + ((q) >> 1) * 16384 +       \
                       ((q) & 1) * 4096 + mi * 2048 + ak0);                 \
      afr[mi][1] = *(const bf16x8*)(As + (PAR) + ((q) >> 1) * 16384 +       \
                       ((q) & 1) * 4096 + mi * 2048 + ak1); } }

#define MMACQ(q)                                                            \
    __builtin_amdgcn_s_setprio(1);                                          \
    _Pragma("unroll") for (int ks = 0; ks < 2; ++ks)                        \
    _Pragma("unroll") for (int mi = 0; mi < 2; ++mi)                        \
    _Pragma("unroll") for (int ni = 0; ni < 4; ++ni)                        \
        acc[(q) * 2 + mi][ni] = __builtin_amdgcn_mfma_f32_16x16x32_bf16(    \
            afr[mi][ks], bfr[ni][ks], acc[(q) * 2 + mi][ni], 0, 0, 0);      \
    __builtin_amdgcn_s_setprio(0);

#define STAGE_A_(H, PAR, GUARD)                                             \
    if (GUARD) { _Pragma("unroll") for (int i = 0; i < 2; ++i) {            \
        __builtin_amdgcn_global_load_lds(                                   \
            (const __attribute__((address_space(1))) void*)gA[H][i],        \
            (__attribute__((address_space(3))) void*)                       \
                (As + (PAR) + (H) * 16384 + i * 8192 + ldsl),               \
            16, 0, 0);                                                      \
        gA[H][i] += 128; } }

#define STAGE_B_(H, PAR, GUARD)                                             \
    if (GUARD) { _Pragma("unroll") for (int i = 0; i < 2; ++i) {            \
        __builtin_amdgcn_global_load_lds(                                   \
            (const __attribute__((address_space(1))) void*)gB[H][i],        \
            (__attribute__((address_space(3))) void*)                       \
                (Bs + (PAR) + (H) * 16384 + i * 8192 + ldsl),               \
            16, 0, 0);                                                      \
        gB[H][i] += 128; } }

#define TILE_BODY(V, PAR, NPAR, VMTXT)                                      \
    STAGE_A_(1, NPAR, (V) + 1 < NT);                                        \
    LOAD_BFR(PAR);                                                          \
    LOAD_AFRQ(0, PAR);                                                      \
    BAR();                                                                  \
    STAGE_B_(0, PAR, (V) + 2 < NT);                                         \
    MMACQ(0);                                                               \
    LOAD_AFRQ(1, PAR);                                                      \
    MMACQ(1);                                                               \
    BAR();                                                                  \
    STAGE_B_(1, PAR, (V) + 2 < NT);                                         \
    STAGE_A_(0, PAR, (V) + 2 < NT);                                         \
    LOAD_AFRQ(2, PAR);                                                      \
    BAR();                                                                  \
    MMACQ(2);                                                               \
    LOAD_AFRQ(3, PAR);                                                      \
    MMACQ(3);                                                               \
    asm volatile("s_waitcnt " VMTXT ::: "memory");                          \
    BAR();

__launch_bounds__(512, 2)
__global__ void stft_gemm_k(const __hip_bfloat16* __restrict__ basis,
                            const __hip_bfloat16* __restrict__ u,
                            const __hip_bfloat16* __restrict__ v,
                            float* __restrict__ out) {
    const int tid  = threadIdx.x;
    const int wave = tid >> 6;
    const int lane = tid & 63;
    const int l16  = lane & 15;
    const int lg   = lane >> 4;
    const int wr   = wave >> 2;
    const int wc   = wave & 3;
    const int f0   = blockIdx.x * BN;
    const int c0   = blockIdx.y * BM;
    const int bb   = blockIdx.z;
    const bool isV = (c0 >= 512);
    const __hip_bfloat16* Bmat =
        (isV ? v : u) + (size_t)bb * NFPAD * KS2;

    char* As = smem;            // 64 KiB (2 buf x 2 half x 16 KiB)
    char* Bs = smem + 65536;    // 64 KiB
    const int ldsl = wave * 1024;

    const int e   = l16 & 7;
    const int ak0 = wr * 8192 + l16 * 128 + ((lg ^ e) * 16);
    const int ak1 = ak0 ^ 64;
    const int bk0 = (wc & 1) * 8192 + (wc >> 1) * 16384 + l16 * 128
                    + ((lg ^ e) * 16);
    const int bk1 = bk0 ^ 64;

    const int kx = (tid & 7) ^ ((tid >> 3) & 7);

    const char* gA[2][2];
    const char* gB[2][2];
    #pragma unroll
    for (int i = 0; i < 2; ++i) {
        int row = tid >> 3;   // 0..63
        gA[0][i] = (const char*)(basis +
            (size_t)(c0 + i * 128 + row) * KS2 + kx * 8);
        gA[1][i] = (const char*)(basis +
            (size_t)(c0 + i * 128 + 64 + row) * KS2 + kx * 8);
    }
    #pragma unroll
    for (int h = 0; h < 2; ++h)
        #pragma unroll
        for (int i = 0; i < 2; ++i) {
            int f = f0 + h * 128 + i * 64 + (tid >> 3);
            gB[h][i] = (const char*)(Bmat + (size_t)f * KS2 + kx * 8);
        }

    f32x4 acc[8][4] = {};
    bf16x8 afr[2][2], bfr[4][2];

    // ---- prologue: tile 0 (4 halves) + B0,B1,A0 of tile 1 ----
    STAGE_A_(0, 0, 1); STAGE_A_(1, 0, 1); STAGE_B_(0, 0, 1); STAGE_B_(1, 0, 1);
    STAGE_B_(0, 32768, 1); STAGE_B_(1, 32768, 1); STAGE_A_(0, 32768, 1);
    asm volatile("s_waitcnt vmcnt(6)" ::: "memory");   // tile 0 resident
    BAR();   // all waves' tile-0 chunks visible -> BFR in tile 0 body safe

    // ---- main loop: tiles 0..5 in even/odd pairs ----
    #pragma unroll 1
    for (int t = 0; t < 3; ++t) {
        TILE_BODY(2 * t,     0,     32768, "vmcnt(6)");
        TILE_BODY(2 * t + 1, 32768, 0,     "vmcnt(6)");
    }
    // ---- tail: tiles 6, 7 (stage guards auto-off) ----
    TILE_BODY(6, 0,     32768, "vmcnt(0)");
    TILE_BODY(7, 32768, 0,     "vmcnt(0)");

    // ---- epilogue: C/D map col=lane&15, row=(lane>>4)*4+reg ----
    const int choff = isV ? 2 : 0;   // sin rows g -> channel g+2
    float* outb = out + (size_t)bb * NCH * NFRM;
    #pragma unroll
    for (int MI = 0; MI < 8; ++MI) {
        int g0 = c0 + wr * 128 + MI * 16 + lg * 4;
        #pragma unroll
        for (int ni = 0; ni < 4; ++ni) {
            int f = f0 + wc * 64 + ni * 16 + l16;
            if (f < NFRM) {
                #pragma unroll
                for (int i = 0; i < 4; ++i)
                    outb[(size_t)(g0 + i + choff) * NFRM + f] = acc[MI][ni][i];
            }
        }
    }
}

extern "C" void kernel_launch(void* const* d_in, const int* in_sizes, int n_in,
                              void* d_out, int out_size, void* d_ws, size_t ws_size,
                              hipStream_t stream) {
    const float* x      = (const float*)d_in[0];
    // d_in[1] = frequency (unused: omega[c] == 2*pi*c/KSZ exactly by setup)
    const float* window = (const float*)d_in[2];

    __hip_bfloat16* basis = (__hip_bfloat16*)d_ws;                 // 1 MiB
    __hip_bfloat16* ub = (__hip_bfloat16*)((char*)d_ws + (size_t)MROWS * KS2 * 2);
    __hip_bfloat16* vb = ub + (size_t)NBATCH * NFPAD * KS2;        // +32 MiB each
    float* outp = (float*)d_out;

    hipFuncSetAttribute((const void*)stft_gemm_k,
                        hipFuncAttributeMaxDynamicSharedMemorySize, LDS_BYTES);

    build_basis_k<<<(MROWS * KS2 + 255) / 256, 256, 0, stream>>>(window, basis);
    prefold_k<<<(NBATCH * NFPAD * 64 + 255) / 256, 256, 0, stream>>>(
        x, window, ub, vb, outp);

    dim3 grid(NFPAD / BN, MROWS / BM, NBATCH);   // 8 x 4 x 16 = 512 blocks
    stft_gemm_k<<<grid, 512, LDS_BYTES, stream>>>(basis, ub, vb, outp);
}

// Round 12
// 72.539 us; speedup vs baseline: 1.1008x; 1.1008x over previous
//
#include <hip/hip_runtime.h>
#include <hip/hip_bf16.h>

// ---- problem constants ----
#define TLEN   524288
#define NBATCH 16
#define KSZ    1024
#define NBINS  513
#define NCH    1026
#define NFRM   2045
#define HOP    256
#define MROWS  1024        // g<512: cos c=g | g 512..1022: sin c=g-511 | g=1023: 0
#define KS2    512         // folded K
#define NFPAD  2048        // u/v frame rows per batch
// ---- GEMM tiling: r1-verified 128x128, BK=64, 4 waves, ~2.7 blk/CU ----
#define BM 128
#define BN 128
#define BK 64
#define NT 8               // K-tiles (512/64)
#define PREP_BASIS_BLKS 2048     // MROWS*KS2/256
#define PREP_FOLD_BLKS  8192     // NBATCH*NFPAD*64/256

typedef __bf16 bf16x8 __attribute__((ext_vector_type(8)));
typedef float  f32x4  __attribute__((ext_vector_type(4)));
typedef unsigned short us8 __attribute__((ext_vector_type(8)));

__device__ __forceinline__ unsigned short f2b(float f) {
    return __builtin_bit_cast(unsigned short, __float2bfloat16(f));
}

// ------------------------------------------------------------------
// Kernel 1 (fused prep): blocks [0,2048) build the folded basis
// (r7-verified math); blocks [2048,10240) prefold x->u,v and compute
// Nyquist rows in-wave (r9/r10-verified math, unchanged).
// ------------------------------------------------------------------
__global__ void prep_k(const float* __restrict__ x,
                       const float* __restrict__ window,
                       __hip_bfloat16* __restrict__ basis,
                       __hip_bfloat16* __restrict__ u,
                       __hip_bfloat16* __restrict__ v,
                       float* __restrict__ out) {
    if (blockIdx.x < PREP_BASIS_BLKS) {
        // ---- folded basis, 1024 x 512 bf16 ----
        int idx = blockIdx.x * 256 + threadIdx.x;
        int g = idx >> 9;
        int k = idx & (KS2 - 1);
        float val = 0.0f;
        if (g < 512) {
            if (k == 0) val = (g & 1) ? -1.0f : 1.0f;
            else {
                int m = (g * k) & (KSZ - 1);
                val = window[k] *
                      cosf((float)m * (6.283185307179586f / (float)KSZ));
            }
        } else if (g < 1023) {
            if (k != 0) {
                int c = g - 511;
                int m = (c * k) & (KSZ - 1);
                val = -window[k] *
                      sinf((float)m * (6.283185307179586f / (float)KSZ));
            }
        }
        basis[idx] = __float2bfloat16(val);
        return;
    }
    // ---- prefold + in-wave Nyquist ----
    int idx = (blockIdx.x - PREP_BASIS_BLKS) * 256 + threadIdx.x;
    int b = idx >> 17;
    int rem = idx & ((1 << 17) - 1);
    int f = rem >> 6;
    int c = rem & 63;                            // k-chunk of 8 == lane
    size_t orow = ((size_t)b * NFPAD + f) * KS2 + c * 8;
    us8 uo = {0, 0, 0, 0, 0, 0, 0, 0};
    us8 vo = {0, 0, 0, 0, 0, 0, 0, 0};
    float nacc = 0.0f;
    if (f < NFRM) {
        const float* xp = x + (size_t)b * TLEN + (size_t)f * HOP;
        float4 fw0 = *(const float4*)(xp + c * 8);
        float4 fw1 = *(const float4*)(xp + c * 8 + 4);
        float4 m0  = *(const float4*)(xp + 1016 - c * 8);
        float4 m1  = *(const float4*)(xp + 1020 - c * 8);
        float fwv[8] = {fw0.x, fw0.y, fw0.z, fw0.w,
                        fw1.x, fw1.y, fw1.z, fw1.w};
        float mv[9];
        mv[0] = m0.x; mv[1] = m0.y; mv[2] = m0.z; mv[3] = m0.w;
        mv[4] = m1.x; mv[5] = m1.y; mv[6] = m1.z; mv[7] = m1.w;
        mv[8] = (c > 0) ? xp[1024 - c * 8] : 0.0f;
        #pragma unroll
        for (int e = 0; e < 8; ++e) {
            float xf = fwv[e];
            float xm = mv[8 - e];
            float uval = xf + xm;
            uo[e] = f2b(uval);
            vo[e] = f2b(xf - xm);
            float wk = window[c * 8 + e];
            nacc += ((e & 1) ? -wk : wk) * uval;
        }
        if (c == 0) {
            float x512 = xp[512];
            uo[0] = f2b(x512);
            vo[0] = 0;
            nacc += x512;
        }
    }
    *(us8*)((unsigned short*)u + orow) = uo;
    *(us8*)((unsigned short*)v + orow) = vo;
    #pragma unroll
    for (int o = 32; o > 0; o >>= 1) nacc += __shfl_xor(nacc, o);
    if (f < NFRM) {
        if (c == 0) out[((size_t)b * NCH + 512) * NFRM + f] = nacc;
        if (c == 1) out[((size_t)b * NCH + 513) * NFRM + f] = 0.0f;
    }
}

// ------------------------------------------------------------------
// Kernel 2: folded GEMM in the r1-verified 128x128 structure.
// 4 waves (2x2 of 64x64), 32 KiB static LDS, 2-barrier K-loop,
// global_load_lds w16, both-sides chunk swizzle (kch = ch ^ (row&7)).
// ~2.7 blocks/CU co-residency is the latency-hiding mechanism (m114).
// A = folded basis [1024][512]; B = u (c0<512) or v [2048][512].
// ------------------------------------------------------------------
__launch_bounds__(256, 2)
__global__ void stft_gemm_k(const __hip_bfloat16* __restrict__ basis,
                            const __hip_bfloat16* __restrict__ u,
                            const __hip_bfloat16* __restrict__ v,
                            float* __restrict__ out) {
    __shared__ __hip_bfloat16 As[BM * BK];   // [row g_local][64 k] 16 KiB
    __shared__ __hip_bfloat16 Bs[BN * BK];   // [row f_local][64 k] 16 KiB

    const int tid  = threadIdx.x;
    const int wave = tid >> 6;
    const int lane = tid & 63;
    const int l16  = lane & 15;
    const int lg   = lane >> 4;
    const int wr   = wave >> 1;          // wave row (g)  0..1
    const int wc   = wave & 1;           // wave col (f)  0..1
    const int f0   = blockIdx.x * BN;
    const int c0   = blockIdx.y * BM;
    const int bb   = blockIdx.z;
    const bool isV = (c0 >= 512);
    const __hip_bfloat16* Bmat =
        (isV ? v : u) + (size_t)bb * NFPAD * KS2;

    f32x4 acc[4][4] = {};

    for (int kt = 0; kt < NT; ++kt) {
        const int k0 = kt * BK;
        // ---- stage A and B tiles (each: 1024 chunks of 16B, 4 iters) ----
        #pragma unroll
        for (int it = 0; it < 4; ++it) {
            int flat = it * 256 + tid;        // chunk index, linear in LDS
            int row  = flat >> 3;             // 0..127
            int ch   = flat & 7;
            int kch  = ch ^ (row & 7);        // pre-swizzled global source
            const __hip_bfloat16* sa =
                basis + (size_t)(c0 + row) * KS2 + k0 + kch * 8;
            __builtin_amdgcn_global_load_lds(
                (const __attribute__((address_space(1))) void*)sa,
                (__attribute__((address_space(3))) void*)
                    ((char*)As + (it * 256 + wave * 64) * 16),
                16, 0, 0);
            const __hip_bfloat16* sb =
                Bmat + (size_t)(f0 + row) * KS2 + k0 + kch * 8;
            __builtin_amdgcn_global_load_lds(
                (const __attribute__((address_space(1))) void*)sb,
                (__attribute__((address_space(3))) void*)
                    ((char*)Bs + (it * 256 + wave * 64) * 16),
                16, 0, 0);
        }
        __syncthreads();   // drains vmcnt before any wave reads LDS

        // ---- compute: 2 k-sub-steps of 32, 16 MFMA each ----
        #pragma unroll
        for (int ks = 0; ks < 2; ++ks) {
            bf16x8 a[4], b[4];
            #pragma unroll
            for (int m = 0; m < 4; ++m) {
                int row  = wr * 64 + m * 16 + l16;
                int slot = row * 8 + ((ks * 4 + lg) ^ (row & 7));
                a[m] = *(const bf16x8*)((const char*)As + slot * 16);
            }
            #pragma unroll
            for (int n = 0; n < 4; ++n) {
                int row  = wc * 64 + n * 16 + l16;
                int slot = row * 8 + ((ks * 4 + lg) ^ (row & 7));
                b[n] = *(const bf16x8*)((const char*)Bs + slot * 16);
            }
            #pragma unroll
            for (int m = 0; m < 4; ++m)
                #pragma unroll
                for (int n = 0; n < 4; ++n)
                    acc[m][n] = __builtin_amdgcn_mfma_f32_16x16x32_bf16(
                        a[m], b[n], acc[m][n], 0, 0, 0);
        }
        __syncthreads();   // compute done before next stage overwrites LDS
    }

    // ---- epilogue: C/D map col=lane&15, row=(lane>>4)*4+reg ----
    const int choff = isV ? 2 : 0;   // sin rows g -> channel g+2
    float* outb = out + (size_t)bb * NCH * NFRM;
    #pragma unroll
    for (int m = 0; m < 4; ++m) {
        int g0 = c0 + wr * 64 + m * 16 + lg * 4;
        #pragma unroll
        for (int n = 0; n < 4; ++n) {
            int f = f0 + wc * 64 + n * 16 + l16;
            if (f < NFRM) {
                #pragma unroll
                for (int i = 0; i < 4; ++i)
                    outb[(size_t)(g0 + i + choff) * NFRM + f] = acc[m][n][i];
            }
        }
    }
}

extern "C" void kernel_launch(void* const* d_in, const int* in_sizes, int n_in,
                              void* d_out, int out_size, void* d_ws, size_t ws_size,
                              hipStream_t stream) {
    const float* x      = (const float*)d_in[0];
    // d_in[1] = frequency (unused: omega[c] == 2*pi*c/KSZ exactly by setup)
    const float* window = (const float*)d_in[2];

    __hip_bfloat16* basis = (__hip_bfloat16*)d_ws;                 // 1 MiB
    __hip_bfloat16* ub = (__hip_bfloat16*)((char*)d_ws + (size_t)MROWS * KS2 * 2);
    __hip_bfloat16* vb = ub + (size_t)NBATCH * NFPAD * KS2;        // +32 MiB each
    float* outp = (float*)d_out;

    prep_k<<<PREP_BASIS_BLKS + PREP_FOLD_BLKS, 256, 0, stream>>>(
        x, window, basis, ub, vb, outp);

    dim3 grid(NFPAD / BN, MROWS / BM, NBATCH);   // 16 x 8 x 16 = 2048 blocks
    stft_gemm_k<<<grid, 256, 0, stream>>>(basis, ub, vb, outp);
}